// Round 5
// baseline (336.441 us; speedup 1.0000x reference)
//
#include <hip/hip_runtime.h>
#include <hip/hip_bf16.h>

// Guided filter, B=8 C=3 H=W=512, RADIUS=15 (31x31 box, zero-pad, /961).
// R5: 4 streaming kernels, NO LDS / NO barriers. Register sliding windows.
//   gfA : H-box 8 stage1 planes {g, g^2, p_c, g*p_c} -> H8 (ws, 64 MB)
//   gfB : V-box (running column sums) + pointwise -> ab float2 (ws+64MB, 50 MB)
//   gfC1: H-box of (a,b) -> abH (aliases H8 region)
//   gfC2: V-box of (a,b) + gray recompute -> out
// Fallback (ws too small): R3 LDS-tiled 2-kernel path.

#define HW 512
#define PLANE 262144
#define RAD 15
#define INV_K2 (1.0f / 961.0f)

// ===================== streaming path =====================

// grid (1,128,8) x 256. wave w -> row y=by*4+w; lane l owns x in [8l, 8l+8).
// window floats: lum[i]/pr[i] = global col (8l-16)+i; output j uses i=j+1..j+31.
__global__ __launch_bounds__(256) void gfA(const float* __restrict__ guide,
                                           const float* __restrict__ inp,
                                           float* __restrict__ H8)
{
    const int tid = threadIdx.x;
    const int w = tid >> 6, l = tid & 63;
    const int y = blockIdx.y * 4 + w;
    const int b = blockIdx.z;
    const int fx0 = 8 * l - 16;

    const float* g0 = guide + (size_t)b * 3 * PLANE + y * HW;
    const float* p0 = inp   + (size_t)b * 3 * PLANE + y * HW;
    float* outb = H8 + (size_t)b * 8 * PLANE + y * HW + 8 * l;

    const float4 z4 = make_float4(0.f, 0.f, 0.f, 0.f);

    float lum[40];
    #pragma unroll
    for (int j = 0; j < 10; ++j) {
        int fx = fx0 + 4 * j;                       // mult of 4; chunk fully in or out
        bool ok = (unsigned)fx < (unsigned)HW;
        float4 r  = ok ? *(const float4*)(g0 + fx)             : z4;
        float4 g  = ok ? *(const float4*)(g0 + PLANE + fx)     : z4;
        float4 bl = ok ? *(const float4*)(g0 + 2 * PLANE + fx) : z4;
        lum[4*j+0] = 0.299f*r.x + 0.587f*g.x + 0.114f*bl.x;
        lum[4*j+1] = 0.299f*r.y + 0.587f*g.y + 0.114f*bl.y;
        lum[4*j+2] = 0.299f*r.z + 0.587f*g.z + 0.114f*bl.z;
        lum[4*j+3] = 0.299f*r.w + 0.587f*g.w + 0.114f*bl.w;
    }
    {   // planes 0:hg  1:hg2
        float s = 0.f, s2 = 0.f;
        float o0[8], o1[8];
        #pragma unroll
        for (int k = 1; k <= 31; ++k) { float v = lum[k]; s += v; s2 += v * v; }
        o0[0] = s; o1[0] = s2;
        #pragma unroll
        for (int j = 1; j < 8; ++j) {
            float vi = lum[j + 31], vo = lum[j];
            s += vi - vo; s2 += vi * vi - vo * vo;
            o0[j] = s; o1[j] = s2;
        }
        *(float4*)(outb)                 = make_float4(o0[0], o0[1], o0[2], o0[3]);
        *(float4*)(outb + 4)             = make_float4(o0[4], o0[5], o0[6], o0[7]);
        *(float4*)(outb + PLANE)         = make_float4(o1[0], o1[1], o1[2], o1[3]);
        *(float4*)(outb + PLANE + 4)     = make_float4(o1[4], o1[5], o1[6], o1[7]);
    }
    #pragma unroll
    for (int c = 0; c < 3; ++c) {       // planes 2+2c:hp  3+2c:hgp
        float pr[40];
        #pragma unroll
        for (int j = 0; j < 10; ++j) {
            int fx = fx0 + 4 * j;
            bool ok = (unsigned)fx < (unsigned)HW;
            float4 v = ok ? *(const float4*)(p0 + c * PLANE + fx) : z4;
            pr[4*j+0] = v.x; pr[4*j+1] = v.y; pr[4*j+2] = v.z; pr[4*j+3] = v.w;
        }
        float s = 0.f, sg = 0.f;
        float o0[8], o1[8];
        #pragma unroll
        for (int k = 1; k <= 31; ++k) { float v = pr[k]; s += v; sg += lum[k] * v; }
        o0[0] = s; o1[0] = sg;
        #pragma unroll
        for (int j = 1; j < 8; ++j) {
            float vi = pr[j + 31], vo = pr[j];
            s  += vi - vo;
            sg += lum[j + 31] * vi - lum[j] * vo;
            o0[j] = s; o1[j] = sg;
        }
        float* op = outb + (size_t)(2 + 2 * c) * PLANE;
        *(float4*)(op)             = make_float4(o0[0], o0[1], o0[2], o0[3]);
        *(float4*)(op + 4)         = make_float4(o0[4], o0[5], o0[6], o0[7]);
        *(float4*)(op + PLANE)     = make_float4(o1[0], o1[1], o1[2], o1[3]);
        *(float4*)(op + PLANE + 4) = make_float4(o1[4], o1[5], o1[6], o1[7]);
    }
}

// grid (2,32,8) x 256. thread = (b, x, 16-row group). Running column sums.
__global__ __launch_bounds__(256) void gfB(const float* __restrict__ H8,
                                           float2* __restrict__ ab)
{
    const int x  = blockIdx.x * 256 + threadIdx.x;
    const int y0 = blockIdx.y * 16;
    const int b  = blockIdx.z;
    const float* base = H8 + (size_t)b * 8 * PLANE + x;

    float s[8];
    #pragma unroll
    for (int p = 0; p < 8; ++p) s[p] = 0.f;

    for (int r = y0 - RAD; r < y0 + RAD; ++r) {      // rows y0-15 .. y0+14
        if ((unsigned)r < (unsigned)HW) {
            #pragma unroll
            for (int p = 0; p < 8; ++p) s[p] += base[p * PLANE + r * HW];
        }
    }
    float2* ab0 = ab + (size_t)b * 3 * PLANE + x;
    #pragma unroll
    for (int i = 0; i < 16; ++i) {
        int y = y0 + i;
        int ra = y + RAD;
        if (ra < HW) {
            #pragma unroll
            for (int p = 0; p < 8; ++p) s[p] += base[p * PLANE + ra * HW];
        }
        float mI = s[0] * INV_K2;
        float vI = s[1] * INV_K2 - mI * mI;
        float rv = 1.0f / (vI + 1e-6f);
        #pragma unroll
        for (int c = 0; c < 3; ++c) {
            float mp   = s[2 + 2 * c] * INV_K2;
            float corr = s[3 + 2 * c] * INV_K2;
            float cov  = corr - mI * mp;
            float aa   = cov * rv;
            float bb   = mp - aa * mI;
            ab0[(size_t)c * PLANE + y * HW] = make_float2(aa, bb);
        }
        int rs = y - RAD;
        if (rs >= 0) {
            #pragma unroll
            for (int p = 0; p < 8; ++p) s[p] -= base[p * PLANE + rs * HW];
        }
    }
}

// grid (1,128,24) x 256. H-box of (a,b). lane l owns 8 px.
__global__ __launch_bounds__(256) void gfC1(const float2* __restrict__ ab,
                                            float2* __restrict__ abH)
{
    const int tid = threadIdx.x;
    const int w = tid >> 6, l = tid & 63;
    const int y  = blockIdx.y * 4 + w;
    const int bc = blockIdx.z;
    const float2* src = ab + (size_t)bc * PLANE + y * HW;
    const int px0 = 8 * l - 16;

    const float4 z4 = make_float4(0.f, 0.f, 0.f, 0.f);
    float av[40], bv[40];
    #pragma unroll
    for (int j = 0; j < 20; ++j) {                   // f4 = 2 float2 pixels
        int px = px0 + 2 * j;                        // even; fully in or out
        bool ok = (unsigned)px < (unsigned)HW;
        float4 v = ok ? *(const float4*)(src + px) : z4;
        av[2*j] = v.x; bv[2*j] = v.y; av[2*j+1] = v.z; bv[2*j+1] = v.w;
    }
    float sa = 0.f, sb = 0.f;
    float oa[8], ob[8];
    #pragma unroll
    for (int k = 1; k <= 31; ++k) { sa += av[k]; sb += bv[k]; }
    oa[0] = sa; ob[0] = sb;
    #pragma unroll
    for (int j = 1; j < 8; ++j) {
        sa += av[j + 31] - av[j];
        sb += bv[j + 31] - bv[j];
        oa[j] = sa; ob[j] = sb;
    }
    float2* dst = abH + (size_t)bc * PLANE + y * HW + 8 * l;
    *(float4*)(dst)     = make_float4(oa[0], ob[0], oa[1], ob[1]);
    *(float4*)(dst + 2) = make_float4(oa[2], ob[2], oa[3], ob[3]);
    *(float4*)(dst + 4) = make_float4(oa[4], ob[4], oa[5], ob[5]);
    *(float4*)(dst + 6) = make_float4(oa[6], ob[6], oa[7], ob[7]);
}

// grid (2,32,24) x 256. V-box of (a,b) + gray + combine.
__global__ __launch_bounds__(256) void gfC2(const float* __restrict__ guide,
                                            const float2* __restrict__ abH,
                                            float* __restrict__ out)
{
    const int x  = blockIdx.x * 256 + threadIdx.x;
    const int y0 = blockIdx.y * 16;
    const int bc = blockIdx.z;
    const int b  = bc / 3;
    const float2* src = abH + (size_t)bc * PLANE + x;
    const float* gb = guide + (size_t)b * 3 * PLANE + x;
    float* op = out + (size_t)bc * PLANE + x;

    float sa = 0.f, sb = 0.f;
    for (int r = y0 - RAD; r < y0 + RAD; ++r) {
        if ((unsigned)r < (unsigned)HW) {
            float2 v = src[r * HW];
            sa += v.x; sb += v.y;
        }
    }
    #pragma unroll
    for (int i = 0; i < 16; ++i) {
        int y = y0 + i;
        int ra = y + RAD;
        if (ra < HW) { float2 v = src[ra * HW]; sa += v.x; sb += v.y; }
        float gray = 0.299f * gb[y * HW] + 0.587f * gb[PLANE + y * HW]
                   + 0.114f * gb[2 * PLANE + y * HW];
        op[y * HW] = sa * INV_K2 * gray + sb * INV_K2;
        int rs = y - RAD;
        if (rs >= 0) { float2 v = src[rs * HW]; sa -= v.x; sb -= v.y; }
    }
}

// ===================== fallback: R3 LDS-tiled path (needs only 50.3 MB ws) ==

#define TILE 32
#define HAL 62
#define GS 63
#define SS 33

__global__ __launch_bounds__(256) void gf_s1_fb(
    const float* __restrict__ guide, const float* __restrict__ inp,
    float2* __restrict__ ab)
{
    __shared__ float gh[HAL * GS];
    __shared__ float ph[HAL * GS];
    __shared__ float h0[HAL * SS];
    __shared__ float h1[HAL * SS];

    const int tx0 = blockIdx.x * TILE;
    const int ty0 = blockIdx.y * TILE;
    const int b   = blockIdx.z;
    const int tid = threadIdx.x;

    const float* gbase = guide + (size_t)b * 3 * PLANE;
    const float* pbase = inp   + (size_t)b * 3 * PLANE;

    int lidx[16], goff[16];
    #pragma unroll
    for (int k = 0; k < 16; ++k) {
        int i = tid + k * 256;
        int r = i / HAL, c = i - r * HAL;
        bool inh = i < HAL * HAL;
        lidx[k] = inh ? (r * GS + c) : -1;
        int y = ty0 + r - RAD, x = tx0 + c - RAD;
        bool ok = inh && ((unsigned)y < (unsigned)HW) && ((unsigned)x < (unsigned)HW);
        goff[k] = ok ? (y * HW + x) : -1;
    }
    float gr_[16], pA[16];
    #pragma unroll
    for (int k = 0; k < 16; ++k) {
        float g = 0.f, p = 0.f;
        if (goff[k] >= 0) {
            int o = goff[k];
            g = 0.299f * gbase[o] + 0.587f * gbase[PLANE + o] + 0.114f * gbase[2 * PLANE + o];
            p = pbase[o];
        }
        gr_[k] = g; pA[k] = p;
    }
    #pragma unroll
    for (int k = 0; k < 16; ++k)
        if (lidx[k] >= 0) { gh[lidx[k]] = gr_[k]; ph[lidx[k]] = pA[k]; }
    __syncthreads();

    const int hr = tid & 63, hq = tid >> 6;
    const bool hact = hr < HAL;
    const int hbase = hr * GS + hq * 8;
    const int obase = hr * SS + hq * 8;
    const int vc = tid & 31, vq = tid >> 5;
    const int vbase = (vq * 4) * SS + vc;

    if (hact) {
        float s0 = 0.f, s1 = 0.f;
        #pragma unroll
        for (int k = 0; k < 31; ++k) { float v = gh[hbase + k]; s0 += v; s1 += v * v; }
        h0[obase] = s0; h1[obase] = s1;
        #pragma unroll
        for (int j = 1; j < 8; ++j) {
            float vi = gh[hbase + j + 30], vo = gh[hbase + j - 1];
            s0 += vi - vo; s1 += vi * vi - vo * vo;
            h0[obase + j] = s0; h1[obase + j] = s1;
        }
    }
    __syncthreads();

    float meanI[4], varI[4];
    {
        float s0 = 0.f, s1 = 0.f;
        #pragma unroll
        for (int k = 0; k < 31; ++k) { s0 += h0[vbase + k * SS]; s1 += h1[vbase + k * SS]; }
        meanI[0] = s0 * INV_K2; varI[0] = s1 * INV_K2 - meanI[0] * meanI[0];
        #pragma unroll
        for (int j = 1; j < 4; ++j) {
            s0 += h0[vbase + (j + 30) * SS] - h0[vbase + (j - 1) * SS];
            s1 += h1[vbase + (j + 30) * SS] - h1[vbase + (j - 1) * SS];
            meanI[j] = s0 * INV_K2; varI[j] = s1 * INV_K2 - meanI[j] * meanI[j];
        }
    }
    float pB[16];
    #pragma unroll
    for (int k = 0; k < 16; ++k)
        pB[k] = (goff[k] >= 0) ? pbase[PLANE + goff[k]] : 0.f;

#define CH_H_FB                                                              \
    if (hact) {                                                              \
        float s0 = 0.f, s1 = 0.f;                                            \
        _Pragma("unroll")                                                    \
        for (int k = 0; k < 31; ++k) {                                       \
            float p = ph[hbase + k], g = gh[hbase + k];                      \
            s0 += p; s1 += g * p;                                            \
        }                                                                    \
        h0[obase] = s0; h1[obase] = s1;                                      \
        _Pragma("unroll")                                                    \
        for (int j = 1; j < 8; ++j) {                                        \
            float pi = ph[hbase + j + 30], po = ph[hbase + j - 1];           \
            float gi = gh[hbase + j + 30], go = gh[hbase + j - 1];           \
            s0 += pi - po; s1 += gi * pi - go * po;                          \
            h0[obase + j] = s0; h1[obase + j] = s1;                          \
        }                                                                    \
    }
#define CH_V_FB(ch)                                                          \
    {                                                                        \
        float s0 = 0.f, s1 = 0.f;                                            \
        _Pragma("unroll")                                                    \
        for (int k = 0; k < 31; ++k) { s0 += h0[vbase + k * SS]; s1 += h1[vbase + k * SS]; } \
        float2* abp = ab + (size_t)(b * 3 + (ch)) * PLANE;                   \
        _Pragma("unroll")                                                    \
        for (int j = 0; j < 4; ++j) {                                        \
            if (j) {                                                         \
                s0 += h0[vbase + (j + 30) * SS] - h0[vbase + (j - 1) * SS];  \
                s1 += h1[vbase + (j + 30) * SS] - h1[vbase + (j - 1) * SS];  \
            }                                                                \
            float mp = s0 * INV_K2, corr = s1 * INV_K2;                      \
            float cov = corr - meanI[j] * mp;                                \
            float aa  = cov / (varI[j] + 1e-6f);                             \
            float bb  = mp - aa * meanI[j];                                  \
            abp[(ty0 + vq * 4 + j) * HW + tx0 + vc] = make_float2(aa, bb);   \
        }                                                                    \
    }

    __syncthreads();
    CH_H_FB
    __syncthreads();
    CH_V_FB(0)
    #pragma unroll
    for (int k = 0; k < 16; ++k) if (lidx[k] >= 0) ph[lidx[k]] = pB[k];
    float pC[16];
    #pragma unroll
    for (int k = 0; k < 16; ++k)
        pC[k] = (goff[k] >= 0) ? pbase[2 * PLANE + goff[k]] : 0.f;
    __syncthreads();
    CH_H_FB
    __syncthreads();
    CH_V_FB(1)
    #pragma unroll
    for (int k = 0; k < 16; ++k) if (lidx[k] >= 0) ph[lidx[k]] = pC[k];
    __syncthreads();
    CH_H_FB
    __syncthreads();
    CH_V_FB(2)
#undef CH_H_FB
#undef CH_V_FB
}

__global__ __launch_bounds__(256) void gf_s2_fb(
    const float* __restrict__ guide, const float2* __restrict__ ab,
    float* __restrict__ out)
{
    __shared__ float ah[HAL * GS];
    __shared__ float bh[HAL * GS];
    __shared__ float h0[HAL * SS];
    __shared__ float h1[HAL * SS];

    const int tx0 = blockIdx.x * TILE;
    const int ty0 = blockIdx.y * TILE;
    const int bc  = blockIdx.z;
    const int b   = bc / 3;
    const int tid = threadIdx.x;

    const float2* abp = ab + (size_t)bc * PLANE;
    const float*  gb  = guide + (size_t)b * 3 * PLANE;
    const int vc = tid & 31, vq = tid >> 5;

    int lidx[16];
    float2 hv[16];
    #pragma unroll
    for (int k = 0; k < 16; ++k) {
        int i = tid + k * 256;
        int r = i / HAL, c = i - r * HAL;
        bool inh = i < HAL * HAL;
        lidx[k] = inh ? (r * GS + c) : -1;
        int y = ty0 + r - RAD, x = tx0 + c - RAD;
        bool ok = inh && ((unsigned)y < (unsigned)HW) && ((unsigned)x < (unsigned)HW);
        hv[k] = ok ? abp[y * HW + x] : make_float2(0.f, 0.f);
    }
    float gcen[4];
    #pragma unroll
    for (int j = 0; j < 4; ++j) {
        int o = (ty0 + vq * 4 + j) * HW + tx0 + vc;
        gcen[j] = 0.299f * gb[o] + 0.587f * gb[PLANE + o] + 0.114f * gb[2 * PLANE + o];
    }
    #pragma unroll
    for (int k = 0; k < 16; ++k)
        if (lidx[k] >= 0) { ah[lidx[k]] = hv[k].x; bh[lidx[k]] = hv[k].y; }
    __syncthreads();

    const int hr = tid & 63, hq = tid >> 6;
    const int hbase = hr * GS + hq * 8;
    const int obase = hr * SS + hq * 8;
    if (hr < HAL) {
        float s0 = 0.f, s1 = 0.f;
        #pragma unroll
        for (int k = 0; k < 31; ++k) { s0 += ah[hbase + k]; s1 += bh[hbase + k]; }
        h0[obase] = s0; h1[obase] = s1;
        #pragma unroll
        for (int j = 1; j < 8; ++j) {
            s0 += ah[hbase + j + 30] - ah[hbase + j - 1];
            s1 += bh[hbase + j + 30] - bh[hbase + j - 1];
            h0[obase + j] = s0; h1[obase + j] = s1;
        }
    }
    __syncthreads();
    {
        const int vbase = (vq * 4) * SS + vc;
        float s0 = 0.f, s1 = 0.f;
        #pragma unroll
        for (int k = 0; k < 31; ++k) { s0 += h0[vbase + k * SS]; s1 += h1[vbase + k * SS]; }
        float* op = out + (size_t)bc * PLANE;
        #pragma unroll
        for (int j = 0; j < 4; ++j) {
            if (j) {
                s0 += h0[vbase + (j + 30) * SS] - h0[vbase + (j - 1) * SS];
                s1 += h1[vbase + (j + 30) * SS] - h1[vbase + (j - 1) * SS];
            }
            int o = (ty0 + vq * 4 + j) * HW + tx0 + vc;
            op[o] = s0 * INV_K2 * gcen[j] + s1 * INV_K2;
        }
    }
}

// ===================== launch =====================

extern "C" void kernel_launch(void* const* d_in, const int* in_sizes, int n_in,
                              void* d_out, int out_size, void* d_ws, size_t ws_size,
                              hipStream_t stream)
{
    const float* guide = (const float*)d_in[0];
    const float* inp   = (const float*)d_in[1];
    float* out = (float*)d_out;

    const size_t H8_BYTES = (size_t)8 * 8 * PLANE * 4;        // 64 MiB
    const size_t AB_BYTES = (size_t)24 * PLANE * 8;           // 48 MiB
    if (ws_size >= H8_BYTES + AB_BYTES) {
        float*  H8  = (float*)d_ws;
        float2* ab  = (float2*)((char*)d_ws + H8_BYTES);
        float2* abH = (float2*)d_ws;     // aliases H8 (dead after gfB)

        gfA <<<dim3(1, 128,  8), 256, 0, stream>>>(guide, inp, H8);
        gfB <<<dim3(2,  32,  8), 256, 0, stream>>>(H8, ab);
        gfC1<<<dim3(1, 128, 24), 256, 0, stream>>>(ab, abH);
        gfC2<<<dim3(2,  32, 24), 256, 0, stream>>>(guide, abH, out);
    } else {
        float2* ab_ws = (float2*)d_ws;   // 50.3 MB
        gf_s1_fb<<<dim3(HW / TILE, HW / TILE, 8),  256, 0, stream>>>(guide, inp, ab_ws);
        gf_s2_fb<<<dim3(HW / TILE, HW / TILE, 24), 256, 0, stream>>>(guide, ab_ws, out);
    }
}

// Round 6
// 204.486 us; speedup vs baseline: 1.6453x; 1.6453x over previous
//
#include <hip/hip_runtime.h>
#include <hip/hip_bf16.h>

// Guided filter, B=8 C=3 H=W=512, RADIUS=15 (31x31 box, zero-pad, /961).
// R6: R5 streaming skeleton, but H-pass kernels are wave-cooperative with a
//     skewed per-wave LDS row buffer (R5's per-lane 40-float register windows
//     spilled to scratch -> 98us latency-bound gfA at VALUBusy 5%).
//   gfA : H-box 8 stage1 planes {g,g^2,p_c,g*p_c} -> H8 (ws, 64 MB)
//   gfB : V-box (running column sums) + pointwise -> ab float2
//   gfC1: H-box of (a,b) -> abH (aliases H8)
//   gfC2: V-box of (a,b) + gray recompute -> out
// Skew map SK(i)=i+(i>>5): stride-8 reads and stride-2/4 writes both hit 32
// distinct banks across 64 lanes (adds +1 bank per 32 dwords).

#define HW 512
#define PLANE 262144
#define RAD 15
#define INV_K2 (1.0f / 961.0f)
#define LROW 584          // skewed buffer: max SK(559)=576, padded

__device__ __forceinline__ int SK(int i) { return i + (i >> 5); }

// ---------------- gfA: H-pass of the 8 stage-1 planes ----------------
// grid (1,128,8) x 256 (4 waves); wave w -> row y = by*4+w; lane l -> cols [8l,8l+8)
__global__ __launch_bounds__(256) void gfA(const float* __restrict__ guide,
                                           const float* __restrict__ inp,
                                           float* __restrict__ H8)
{
    __shared__ float lds[4][4 * LROW];
    const int tid = threadIdx.x, w = tid >> 6, l = tid & 63;
    const int y = blockIdx.y * 4 + w;
    const int b = blockIdx.z;

    float* LG  = lds[w];
    float* LP0 = LG + LROW;
    float* LP1 = LG + 2 * LROW;
    float* LP2 = LG + 3 * LROW;

    const float* gR = guide + (size_t)b * 3 * PLANE + y * HW;
    const float* gG = gR + PLANE;
    const float* gB = gR + 2 * PLANE;
    const float* q0 = inp + (size_t)b * 3 * PLANE + y * HW;
    const float* q1 = q0 + PLANE;
    const float* q2 = q0 + 2 * PLANE;

    const float4 z4 = make_float4(0.f, 0.f, 0.f, 0.f);

    // stage padded row (cols -16..543 -> idx 0..559), 140 float4 chunks
    #pragma unroll
    for (int rnd = 0; rnd < 3; ++rnd) {
        if (rnd < 2 || l < 12) {
            int q = l + rnd * 64;
            int col = 4 * q - 16;                    // mult of 4; in iff 0<=col<=508
            bool ok = (unsigned)col < (unsigned)HW;
            float4 r  = ok ? *(const float4*)(gR + col) : z4;
            float4 g  = ok ? *(const float4*)(gG + col) : z4;
            float4 bl = ok ? *(const float4*)(gB + col) : z4;
            float4 v0 = ok ? *(const float4*)(q0 + col) : z4;
            float4 v1 = ok ? *(const float4*)(q1 + col) : z4;
            float4 v2 = ok ? *(const float4*)(q2 + col) : z4;
            int i0 = 4 * q;
            LG[SK(i0+0)] = 0.299f*r.x + 0.587f*g.x + 0.114f*bl.x;
            LG[SK(i0+1)] = 0.299f*r.y + 0.587f*g.y + 0.114f*bl.y;
            LG[SK(i0+2)] = 0.299f*r.z + 0.587f*g.z + 0.114f*bl.z;
            LG[SK(i0+3)] = 0.299f*r.w + 0.587f*g.w + 0.114f*bl.w;
            LP0[SK(i0+0)] = v0.x; LP0[SK(i0+1)] = v0.y; LP0[SK(i0+2)] = v0.z; LP0[SK(i0+3)] = v0.w;
            LP1[SK(i0+0)] = v1.x; LP1[SK(i0+1)] = v1.y; LP1[SK(i0+2)] = v1.z; LP1[SK(i0+3)] = v1.w;
            LP2[SK(i0+0)] = v2.x; LP2[SK(i0+1)] = v2.y; LP2[SK(i0+2)] = v2.z; LP2[SK(i0+3)] = v2.w;
        }
    }
    // no barrier: each wave reads only its own LDS region (compiler waitcnts)

    float* outb = H8 + (size_t)b * 8 * PLANE + y * HW + 8 * l;
    const int t0 = 8 * l;      // output j taps: idx t0+j+1 .. t0+j+31

    {   // pair {g, g^2} -> planes 0,1
        float s0 = 0.f, s1 = 0.f, o0[8], o1[8];
        #pragma unroll
        for (int k = 1; k <= 31; ++k) { float g = LG[SK(t0 + k)]; s0 += g; s1 += g * g; }
        o0[0] = s0; o1[0] = s1;
        #pragma unroll
        for (int j = 1; j < 8; ++j) {
            float gi = LG[SK(t0 + j + 31)], go = LG[SK(t0 + j)];
            s0 += gi - go; s1 += gi * gi - go * go;
            o0[j] = s0; o1[j] = s1;
        }
        *(float4*)(outb)             = make_float4(o0[0], o0[1], o0[2], o0[3]);
        *(float4*)(outb + 4)         = make_float4(o0[4], o0[5], o0[6], o0[7]);
        *(float4*)(outb + PLANE)     = make_float4(o1[0], o1[1], o1[2], o1[3]);
        *(float4*)(outb + PLANE + 4) = make_float4(o1[4], o1[5], o1[6], o1[7]);
    }
#define PAIR_C(LP, c)                                                         \
    {                                                                         \
        float s0 = 0.f, s1 = 0.f, o0[8], o1[8];                               \
        _Pragma("unroll")                                                     \
        for (int k = 1; k <= 31; ++k) {                                       \
            float g = LG[SK(t0 + k)], p = (LP)[SK(t0 + k)];                   \
            s0 += p; s1 += g * p;                                             \
        }                                                                     \
        o0[0] = s0; o1[0] = s1;                                               \
        _Pragma("unroll")                                                     \
        for (int j = 1; j < 8; ++j) {                                         \
            float gi = LG[SK(t0 + j + 31)], go = LG[SK(t0 + j)];              \
            float pi = (LP)[SK(t0 + j + 31)], po = (LP)[SK(t0 + j)];          \
            s0 += pi - po; s1 += gi * pi - go * po;                           \
            o0[j] = s0; o1[j] = s1;                                           \
        }                                                                     \
        float* op = outb + (size_t)(2 + 2 * (c)) * PLANE;                     \
        *(float4*)(op)             = make_float4(o0[0], o0[1], o0[2], o0[3]); \
        *(float4*)(op + 4)         = make_float4(o0[4], o0[5], o0[6], o0[7]); \
        *(float4*)(op + PLANE)     = make_float4(o1[0], o1[1], o1[2], o1[3]); \
        *(float4*)(op + PLANE + 4) = make_float4(o1[4], o1[5], o1[6], o1[7]); \
    }
    PAIR_C(LP0, 0)
    PAIR_C(LP1, 1)
    PAIR_C(LP2, 2)
#undef PAIR_C
}

// ---------------- gfB: V-pass + pointwise -> ab ----------------
// grid (2,32,8) x 256. thread = (b, x, 16-row strip). Running column sums.
__global__ __launch_bounds__(256) void gfB(const float* __restrict__ H8,
                                           float2* __restrict__ ab)
{
    const int x  = blockIdx.x * 256 + threadIdx.x;
    const int y0 = blockIdx.y * 16;
    const int b  = blockIdx.z;
    const float* base = H8 + (size_t)b * 8 * PLANE + x;

    float s[8];
    #pragma unroll
    for (int p = 0; p < 8; ++p) s[p] = 0.f;

    for (int r = y0 - RAD; r < y0 + RAD; ++r) {
        if ((unsigned)r < (unsigned)HW) {
            #pragma unroll
            for (int p = 0; p < 8; ++p) s[p] += base[p * PLANE + r * HW];
        }
    }
    float2* ab0 = ab + (size_t)b * 3 * PLANE + x;
    #pragma unroll
    for (int i = 0; i < 16; ++i) {
        int y = y0 + i;
        int ra = y + RAD;
        if (ra < HW) {
            #pragma unroll
            for (int p = 0; p < 8; ++p) s[p] += base[p * PLANE + ra * HW];
        }
        float mI = s[0] * INV_K2;
        float vI = s[1] * INV_K2 - mI * mI;
        float rv = 1.0f / (vI + 1e-6f);
        #pragma unroll
        for (int c = 0; c < 3; ++c) {
            float mp   = s[2 + 2 * c] * INV_K2;
            float corr = s[3 + 2 * c] * INV_K2;
            float cov  = corr - mI * mp;
            float aa   = cov * rv;
            float bb   = mp - aa * mI;
            ab0[(size_t)c * PLANE + y * HW] = make_float2(aa, bb);
        }
        int rs = y - RAD;
        if (rs >= 0) {
            #pragma unroll
            for (int p = 0; p < 8; ++p) s[p] -= base[p * PLANE + rs * HW];
        }
    }
}

// ---------------- gfC1: H-pass of (a,b) ----------------
// grid (1,128,24) x 256 (4 waves); wave -> row; LDS-staged a,b rows.
__global__ __launch_bounds__(256) void gfC1(const float2* __restrict__ ab,
                                            float2* __restrict__ abH)
{
    __shared__ float lds[4][2 * LROW];
    const int tid = threadIdx.x, w = tid >> 6, l = tid & 63;
    const int y  = blockIdx.y * 4 + w;
    const int bc = blockIdx.z;

    float* LA = lds[w];
    float* LB = LA + LROW;
    const float2* src = ab + (size_t)bc * PLANE + y * HW;
    const float4 z4 = make_float4(0.f, 0.f, 0.f, 0.f);

    // stage 560 px (280 float4 chunks of 2 px)
    #pragma unroll
    for (int rnd = 0; rnd < 5; ++rnd) {
        if (rnd < 4 || l < 24) {
            int q = l + rnd * 64;
            int px = 2 * q - 16;                     // even; in iff 0<=px<=510
            bool ok = (unsigned)px < (unsigned)HW;
            float4 v = ok ? *(const float4*)(src + px) : z4;
            int i0 = 2 * q;
            LA[SK(i0)]     = v.x; LB[SK(i0)]     = v.y;
            LA[SK(i0 + 1)] = v.z; LB[SK(i0 + 1)] = v.w;
        }
    }

    const int t0 = 8 * l;
    float sa = 0.f, sb = 0.f, oa[8], ob[8];
    #pragma unroll
    for (int k = 1; k <= 31; ++k) { sa += LA[SK(t0 + k)]; sb += LB[SK(t0 + k)]; }
    oa[0] = sa; ob[0] = sb;
    #pragma unroll
    for (int j = 1; j < 8; ++j) {
        sa += LA[SK(t0 + j + 31)] - LA[SK(t0 + j)];
        sb += LB[SK(t0 + j + 31)] - LB[SK(t0 + j)];
        oa[j] = sa; ob[j] = sb;
    }
    float2* dst = abH + (size_t)bc * PLANE + y * HW + 8 * l;
    *(float4*)(dst)     = make_float4(oa[0], ob[0], oa[1], ob[1]);
    *(float4*)(dst + 2) = make_float4(oa[2], ob[2], oa[3], ob[3]);
    *(float4*)(dst + 4) = make_float4(oa[4], ob[4], oa[5], ob[5]);
    *(float4*)(dst + 6) = make_float4(oa[6], ob[6], oa[7], ob[7]);
}

// ---------------- gfC2: V-pass of (a,b) + gray + combine ----------------
// grid (2,32,24) x 256.
__global__ __launch_bounds__(256) void gfC2(const float* __restrict__ guide,
                                            const float2* __restrict__ abH,
                                            float* __restrict__ out)
{
    const int x  = blockIdx.x * 256 + threadIdx.x;
    const int y0 = blockIdx.y * 16;
    const int bc = blockIdx.z;
    const int b  = bc / 3;
    const float2* src = abH + (size_t)bc * PLANE + x;
    const float* gb = guide + (size_t)b * 3 * PLANE + x;
    float* op = out + (size_t)bc * PLANE + x;

    float sa = 0.f, sb = 0.f;
    for (int r = y0 - RAD; r < y0 + RAD; ++r) {
        if ((unsigned)r < (unsigned)HW) {
            float2 v = src[r * HW];
            sa += v.x; sb += v.y;
        }
    }
    #pragma unroll
    for (int i = 0; i < 16; ++i) {
        int y = y0 + i;
        int ra = y + RAD;
        if (ra < HW) { float2 v = src[ra * HW]; sa += v.x; sb += v.y; }
        float gray = 0.299f * gb[y * HW] + 0.587f * gb[PLANE + y * HW]
                   + 0.114f * gb[2 * PLANE + y * HW];
        op[y * HW] = sa * INV_K2 * gray + sb * INV_K2;
        int rs = y - RAD;
        if (rs >= 0) { float2 v = src[rs * HW]; sa -= v.x; sb -= v.y; }
    }
}

// ===================== fallback: R3 LDS-tiled path (50.3 MB ws) ==========

#define TILE 32
#define HAL 62
#define GS 63
#define SS 33

__global__ __launch_bounds__(256) void gf_s1_fb(
    const float* __restrict__ guide, const float* __restrict__ inp,
    float2* __restrict__ ab)
{
    __shared__ float gh[HAL * GS];
    __shared__ float ph[HAL * GS];
    __shared__ float h0[HAL * SS];
    __shared__ float h1[HAL * SS];

    const int tx0 = blockIdx.x * TILE;
    const int ty0 = blockIdx.y * TILE;
    const int b   = blockIdx.z;
    const int tid = threadIdx.x;

    const float* gbase = guide + (size_t)b * 3 * PLANE;
    const float* pbase = inp   + (size_t)b * 3 * PLANE;

    int lidx[16], goff[16];
    #pragma unroll
    for (int k = 0; k < 16; ++k) {
        int i = tid + k * 256;
        int r = i / HAL, c = i - r * HAL;
        bool inh = i < HAL * HAL;
        lidx[k] = inh ? (r * GS + c) : -1;
        int y = ty0 + r - RAD, x = tx0 + c - RAD;
        bool ok = inh && ((unsigned)y < (unsigned)HW) && ((unsigned)x < (unsigned)HW);
        goff[k] = ok ? (y * HW + x) : -1;
    }
    float gr_[16], pA[16];
    #pragma unroll
    for (int k = 0; k < 16; ++k) {
        float g = 0.f, p = 0.f;
        if (goff[k] >= 0) {
            int o = goff[k];
            g = 0.299f * gbase[o] + 0.587f * gbase[PLANE + o] + 0.114f * gbase[2 * PLANE + o];
            p = pbase[o];
        }
        gr_[k] = g; pA[k] = p;
    }
    #pragma unroll
    for (int k = 0; k < 16; ++k)
        if (lidx[k] >= 0) { gh[lidx[k]] = gr_[k]; ph[lidx[k]] = pA[k]; }
    __syncthreads();

    const int hr = tid & 63, hq = tid >> 6;
    const bool hact = hr < HAL;
    const int hbase = hr * GS + hq * 8;
    const int obase = hr * SS + hq * 8;
    const int vc = tid & 31, vq = tid >> 5;
    const int vbase = (vq * 4) * SS + vc;

    if (hact) {
        float s0 = 0.f, s1 = 0.f;
        #pragma unroll
        for (int k = 0; k < 31; ++k) { float v = gh[hbase + k]; s0 += v; s1 += v * v; }
        h0[obase] = s0; h1[obase] = s1;
        #pragma unroll
        for (int j = 1; j < 8; ++j) {
            float vi = gh[hbase + j + 30], vo = gh[hbase + j - 1];
            s0 += vi - vo; s1 += vi * vi - vo * vo;
            h0[obase + j] = s0; h1[obase + j] = s1;
        }
    }
    __syncthreads();

    float meanI[4], varI[4];
    {
        float s0 = 0.f, s1 = 0.f;
        #pragma unroll
        for (int k = 0; k < 31; ++k) { s0 += h0[vbase + k * SS]; s1 += h1[vbase + k * SS]; }
        meanI[0] = s0 * INV_K2; varI[0] = s1 * INV_K2 - meanI[0] * meanI[0];
        #pragma unroll
        for (int j = 1; j < 4; ++j) {
            s0 += h0[vbase + (j + 30) * SS] - h0[vbase + (j - 1) * SS];
            s1 += h1[vbase + (j + 30) * SS] - h1[vbase + (j - 1) * SS];
            meanI[j] = s0 * INV_K2; varI[j] = s1 * INV_K2 - meanI[j] * meanI[j];
        }
    }
    float pB[16];
    #pragma unroll
    for (int k = 0; k < 16; ++k)
        pB[k] = (goff[k] >= 0) ? pbase[PLANE + goff[k]] : 0.f;

#define CH_H_FB                                                              \
    if (hact) {                                                              \
        float s0 = 0.f, s1 = 0.f;                                            \
        _Pragma("unroll")                                                    \
        for (int k = 0; k < 31; ++k) {                                       \
            float p = ph[hbase + k], g = gh[hbase + k];                      \
            s0 += p; s1 += g * p;                                            \
        }                                                                    \
        h0[obase] = s0; h1[obase] = s1;                                      \
        _Pragma("unroll")                                                    \
        for (int j = 1; j < 8; ++j) {                                        \
            float pi = ph[hbase + j + 30], po = ph[hbase + j - 1];           \
            float gi = gh[hbase + j + 30], go = gh[hbase + j - 1];           \
            s0 += pi - po; s1 += gi * pi - go * po;                          \
            h0[obase + j] = s0; h1[obase + j] = s1;                          \
        }                                                                    \
    }
#define CH_V_FB(ch)                                                          \
    {                                                                        \
        float s0 = 0.f, s1 = 0.f;                                            \
        _Pragma("unroll")                                                    \
        for (int k = 0; k < 31; ++k) { s0 += h0[vbase + k * SS]; s1 += h1[vbase + k * SS]; } \
        float2* abp = ab + (size_t)(b * 3 + (ch)) * PLANE;                   \
        _Pragma("unroll")                                                    \
        for (int j = 0; j < 4; ++j) {                                        \
            if (j) {                                                         \
                s0 += h0[vbase + (j + 30) * SS] - h0[vbase + (j - 1) * SS];  \
                s1 += h1[vbase + (j + 30) * SS] - h1[vbase + (j - 1) * SS];  \
            }                                                                \
            float mp = s0 * INV_K2, corr = s1 * INV_K2;                      \
            float cov = corr - meanI[j] * mp;                                \
            float aa  = cov / (varI[j] + 1e-6f);                             \
            float bb  = mp - aa * meanI[j];                                  \
            abp[(ty0 + vq * 4 + j) * HW + tx0 + vc] = make_float2(aa, bb);   \
        }                                                                    \
    }

    __syncthreads();
    CH_H_FB
    __syncthreads();
    CH_V_FB(0)
    #pragma unroll
    for (int k = 0; k < 16; ++k) if (lidx[k] >= 0) ph[lidx[k]] = pB[k];
    float pC[16];
    #pragma unroll
    for (int k = 0; k < 16; ++k)
        pC[k] = (goff[k] >= 0) ? pbase[2 * PLANE + goff[k]] : 0.f;
    __syncthreads();
    CH_H_FB
    __syncthreads();
    CH_V_FB(1)
    #pragma unroll
    for (int k = 0; k < 16; ++k) if (lidx[k] >= 0) ph[lidx[k]] = pC[k];
    __syncthreads();
    CH_H_FB
    __syncthreads();
    CH_V_FB(2)
#undef CH_H_FB
#undef CH_V_FB
}

__global__ __launch_bounds__(256) void gf_s2_fb(
    const float* __restrict__ guide, const float2* __restrict__ ab,
    float* __restrict__ out)
{
    __shared__ float ah[HAL * GS];
    __shared__ float bh[HAL * GS];
    __shared__ float h0[HAL * SS];
    __shared__ float h1[HAL * SS];

    const int tx0 = blockIdx.x * TILE;
    const int ty0 = blockIdx.y * TILE;
    const int bc  = blockIdx.z;
    const int b   = bc / 3;
    const int tid = threadIdx.x;

    const float2* abp = ab + (size_t)bc * PLANE;
    const float*  gb  = guide + (size_t)b * 3 * PLANE;
    const int vc = tid & 31, vq = tid >> 5;

    int lidx[16];
    float2 hv[16];
    #pragma unroll
    for (int k = 0; k < 16; ++k) {
        int i = tid + k * 256;
        int r = i / HAL, c = i - r * HAL;
        bool inh = i < HAL * HAL;
        lidx[k] = inh ? (r * GS + c) : -1;
        int y = ty0 + r - RAD, x = tx0 + c - RAD;
        bool ok = inh && ((unsigned)y < (unsigned)HW) && ((unsigned)x < (unsigned)HW);
        hv[k] = ok ? abp[y * HW + x] : make_float2(0.f, 0.f);
    }
    float gcen[4];
    #pragma unroll
    for (int j = 0; j < 4; ++j) {
        int o = (ty0 + vq * 4 + j) * HW + tx0 + vc;
        gcen[j] = 0.299f * gb[o] + 0.587f * gb[PLANE + o] + 0.114f * gb[2 * PLANE + o];
    }
    #pragma unroll
    for (int k = 0; k < 16; ++k)
        if (lidx[k] >= 0) { ah[lidx[k]] = hv[k].x; bh[lidx[k]] = hv[k].y; }
    __syncthreads();

    const int hr = tid & 63, hq = tid >> 6;
    const int hbase = hr * GS + hq * 8;
    const int obase = hr * SS + hq * 8;
    if (hr < HAL) {
        float s0 = 0.f, s1 = 0.f;
        #pragma unroll
        for (int k = 0; k < 31; ++k) { s0 += ah[hbase + k]; s1 += bh[hbase + k]; }
        h0[obase] = s0; h1[obase] = s1;
        #pragma unroll
        for (int j = 1; j < 8; ++j) {
            s0 += ah[hbase + j + 30] - ah[hbase + j - 1];
            s1 += bh[hbase + j + 30] - bh[hbase + j - 1];
            h0[obase + j] = s0; h1[obase + j] = s1;
        }
    }
    __syncthreads();
    {
        const int vbase = (vq * 4) * SS + vc;
        float s0 = 0.f, s1 = 0.f;
        #pragma unroll
        for (int k = 0; k < 31; ++k) { s0 += h0[vbase + k * SS]; s1 += h1[vbase + k * SS]; }
        float* op = out + (size_t)bc * PLANE;
        #pragma unroll
        for (int j = 0; j < 4; ++j) {
            if (j) {
                s0 += h0[vbase + (j + 30) * SS] - h0[vbase + (j - 1) * SS];
                s1 += h1[vbase + (j + 30) * SS] - h1[vbase + (j - 1) * SS];
            }
            int o = (ty0 + vq * 4 + j) * HW + tx0 + vc;
            op[o] = s0 * INV_K2 * gcen[j] + s1 * INV_K2;
        }
    }
}

// ===================== launch =====================

extern "C" void kernel_launch(void* const* d_in, const int* in_sizes, int n_in,
                              void* d_out, int out_size, void* d_ws, size_t ws_size,
                              hipStream_t stream)
{
    const float* guide = (const float*)d_in[0];
    const float* inp   = (const float*)d_in[1];
    float* out = (float*)d_out;

    const size_t H8_BYTES = (size_t)8 * 8 * PLANE * 4;        // 64 MiB
    const size_t AB_BYTES = (size_t)24 * PLANE * 8;           // 48 MiB
    if (ws_size >= H8_BYTES + AB_BYTES) {
        float*  H8  = (float*)d_ws;
        float2* ab  = (float2*)((char*)d_ws + H8_BYTES);
        float2* abH = (float2*)d_ws;     // aliases H8 (dead after gfB)

        gfA <<<dim3(1, 128,  8), 256, 0, stream>>>(guide, inp, H8);
        gfB <<<dim3(2,  32,  8), 256, 0, stream>>>(H8, ab);
        gfC1<<<dim3(1, 128, 24), 256, 0, stream>>>(ab, abH);
        gfC2<<<dim3(2,  32, 24), 256, 0, stream>>>(guide, abH, out);
    } else {
        float2* ab_ws = (float2*)d_ws;   // 50.3 MB
        gf_s1_fb<<<dim3(HW / TILE, HW / TILE, 8),  256, 0, stream>>>(guide, inp, ab_ws);
        gf_s2_fb<<<dim3(HW / TILE, HW / TILE, 24), 256, 0, stream>>>(guide, ab_ws, out);
    }
}

// Round 7
// 175.549 us; speedup vs baseline: 1.9165x; 1.1648x over previous
//
#include <hip/hip_runtime.h>
#include <hip/hip_bf16.h>
#include <hip/hip_fp16.h>

// Guided filter, B=8 C=3 H=W=512, RADIUS=15 (31x31 box, zero-pad, /961).
// R7: R6 structure, fp16 intermediates to halve plane traffic (gfB was
//     BW-bound at 3.9TB/s on f32 H8).
//   gfA : H-box 8 stage1 planes -> H8 as 4 half2-pair planes {s,s'} + gray(fp16)
//   gfB : V-box (running column sums) + pointwise -> ab half2 {a,b}
//   gfC1: H-box of (a,b) -> abH half2
//   gfC2: V-box of (a,b) + gray(fp16) + combine -> out f32
// ws layout: H8 32MiB | gray 4MiB | ab 24MiB | abH 24MiB = 84MiB.

#define HW 512
#define PLANE 262144
#define RAD 15
#define INV_K2 (1.0f / 961.0f)
#define LROW 584          // skewed row buffer: max SK(559)=576, padded

__device__ __forceinline__ int SK(int i) { return i + (i >> 5); }
__device__ __forceinline__ unsigned h2u(__half2 h) { return *(unsigned*)&h; }

// ---------------- gfA: H-pass of the 8 stage-1 planes + gray save ----------
// grid (1,128,8) x 256 (4 waves); wave w -> row y = by*4+w; lane l -> [8l,8l+8)
__global__ __launch_bounds__(256) void gfA(const float* __restrict__ guide,
                                           const float* __restrict__ inp,
                                           __half2* __restrict__ H8,
                                           __half* __restrict__ gray)
{
    __shared__ float lds[4][4 * LROW];
    const int tid = threadIdx.x, w = tid >> 6, l = tid & 63;
    const int y = blockIdx.y * 4 + w;
    const int b = blockIdx.z;

    float* LG  = lds[w];
    float* LP0 = LG + LROW;
    float* LP1 = LG + 2 * LROW;
    float* LP2 = LG + 3 * LROW;

    const float* gR = guide + (size_t)b * 3 * PLANE + y * HW;
    const float* gG = gR + PLANE;
    const float* gB = gR + 2 * PLANE;
    const float* q0 = inp + (size_t)b * 3 * PLANE + y * HW;
    const float* q1 = q0 + PLANE;
    const float* q2 = q0 + 2 * PLANE;
    __half* grow = gray + (size_t)b * PLANE + y * HW;

    const float4 z4 = make_float4(0.f, 0.f, 0.f, 0.f);

    // stage padded row (cols -16..543 -> idx 0..559), 140 float4 chunks
    #pragma unroll
    for (int rnd = 0; rnd < 3; ++rnd) {
        if (rnd < 2 || l < 12) {
            int q = l + rnd * 64;
            int col = 4 * q - 16;                    // mult of 4
            bool ok = (unsigned)col < (unsigned)HW;
            float4 r  = ok ? *(const float4*)(gR + col) : z4;
            float4 g  = ok ? *(const float4*)(gG + col) : z4;
            float4 bl = ok ? *(const float4*)(gB + col) : z4;
            float4 v0 = ok ? *(const float4*)(q0 + col) : z4;
            float4 v1 = ok ? *(const float4*)(q1 + col) : z4;
            float4 v2 = ok ? *(const float4*)(q2 + col) : z4;
            float l0 = 0.299f*r.x + 0.587f*g.x + 0.114f*bl.x;
            float l1 = 0.299f*r.y + 0.587f*g.y + 0.114f*bl.y;
            float l2 = 0.299f*r.z + 0.587f*g.z + 0.114f*bl.z;
            float l3 = 0.299f*r.w + 0.587f*g.w + 0.114f*bl.w;
            int i0 = 4 * q;
            LG[SK(i0+0)] = l0; LG[SK(i0+1)] = l1; LG[SK(i0+2)] = l2; LG[SK(i0+3)] = l3;
            LP0[SK(i0+0)] = v0.x; LP0[SK(i0+1)] = v0.y; LP0[SK(i0+2)] = v0.z; LP0[SK(i0+3)] = v0.w;
            LP1[SK(i0+0)] = v1.x; LP1[SK(i0+1)] = v1.y; LP1[SK(i0+2)] = v1.z; LP1[SK(i0+3)] = v1.w;
            LP2[SK(i0+0)] = v2.x; LP2[SK(i0+1)] = v2.y; LP2[SK(i0+2)] = v2.z; LP2[SK(i0+3)] = v2.w;
            if (ok) {       // save gray plane (center cols only) as fp16
                __half2* gp = (__half2*)(grow + col);
                gp[0] = __floats2half2_rn(l0, l1);
                gp[1] = __floats2half2_rn(l2, l3);
            }
        }
    }
    // no barrier: each wave touches only lds[w]

    __half2* outb = H8 + ((size_t)b * 4) * PLANE + y * HW + 8 * l;
    const int t0 = 8 * l;      // output j taps: idx t0+j+1 .. t0+j+31

#define EMIT_PAIR(pairIdx)                                                    \
    {                                                                         \
        unsigned u[8];                                                        \
        _Pragma("unroll")                                                     \
        for (int j = 0; j < 8; ++j) {                                         \
            __half2 h = __floats2half2_rn(o0[j], o1[j]);                      \
            u[j] = h2u(h);                                                    \
        }                                                                     \
        uint4* dst = (uint4*)(outb + (size_t)(pairIdx) * PLANE);              \
        dst[0] = make_uint4(u[0], u[1], u[2], u[3]);                          \
        dst[1] = make_uint4(u[4], u[5], u[6], u[7]);                          \
    }

    {   // pair 0: {g, g^2}
        float s0 = 0.f, s1 = 0.f, o0[8], o1[8];
        #pragma unroll
        for (int k = 1; k <= 31; ++k) { float g = LG[SK(t0 + k)]; s0 += g; s1 += g * g; }
        o0[0] = s0; o1[0] = s1;
        #pragma unroll
        for (int j = 1; j < 8; ++j) {
            float gi = LG[SK(t0 + j + 31)], go = LG[SK(t0 + j)];
            s0 += gi - go; s1 += gi * gi - go * go;
            o0[j] = s0; o1[j] = s1;
        }
        EMIT_PAIR(0)
    }
#define PAIR_C(LP, c)                                                         \
    {                                                                         \
        float s0 = 0.f, s1 = 0.f, o0[8], o1[8];                               \
        _Pragma("unroll")                                                     \
        for (int k = 1; k <= 31; ++k) {                                       \
            float g = LG[SK(t0 + k)], p = (LP)[SK(t0 + k)];                   \
            s0 += p; s1 += g * p;                                             \
        }                                                                     \
        o0[0] = s0; o1[0] = s1;                                               \
        _Pragma("unroll")                                                     \
        for (int j = 1; j < 8; ++j) {                                         \
            float gi = LG[SK(t0 + j + 31)], go = LG[SK(t0 + j)];              \
            float pi = (LP)[SK(t0 + j + 31)], po = (LP)[SK(t0 + j)];          \
            s0 += pi - po; s1 += gi * pi - go * po;                           \
            o0[j] = s0; o1[j] = s1;                                           \
        }                                                                     \
        EMIT_PAIR(1 + (c))                                                    \
    }
    PAIR_C(LP0, 0)
    PAIR_C(LP1, 1)
    PAIR_C(LP2, 2)
#undef PAIR_C
#undef EMIT_PAIR
}

// ---------------- gfB: V-pass + pointwise -> ab (half2) ----------------
// grid (2,32,8) x 256. thread = (b, x, 16-row strip). Running column sums.
__global__ __launch_bounds__(256) void gfB(const __half2* __restrict__ H8,
                                           __half2* __restrict__ ab)
{
    const int x  = blockIdx.x * 256 + threadIdx.x;
    const int y0 = blockIdx.y * 16;
    const int b  = blockIdx.z;
    const __half2* base = H8 + (size_t)b * 4 * PLANE + x;

    float2 s[4];
    #pragma unroll
    for (int p = 0; p < 4; ++p) s[p] = make_float2(0.f, 0.f);

    for (int r = y0 - RAD; r < y0 + RAD; ++r) {
        if ((unsigned)r < (unsigned)HW) {
            #pragma unroll
            for (int p = 0; p < 4; ++p) {
                float2 f = __half22float2(base[p * PLANE + r * HW]);
                s[p].x += f.x; s[p].y += f.y;
            }
        }
    }
    __half2* ab0 = ab + (size_t)b * 3 * PLANE + x;
    #pragma unroll
    for (int i = 0; i < 16; ++i) {
        int y = y0 + i;
        int ra = y + RAD;
        if (ra < HW) {
            #pragma unroll
            for (int p = 0; p < 4; ++p) {
                float2 f = __half22float2(base[p * PLANE + ra * HW]);
                s[p].x += f.x; s[p].y += f.y;
            }
        }
        float mI = s[0].x * INV_K2;
        float vI = s[0].y * INV_K2 - mI * mI;
        float rv = 1.0f / (vI + 1e-6f);
        #pragma unroll
        for (int c = 0; c < 3; ++c) {
            float mp   = s[1 + c].x * INV_K2;
            float corr = s[1 + c].y * INV_K2;
            float cov  = corr - mI * mp;
            float aa   = cov * rv;
            float bb   = mp - aa * mI;
            ab0[(size_t)c * PLANE + y * HW] = __floats2half2_rn(aa, bb);
        }
        int rs = y - RAD;
        if (rs >= 0) {
            #pragma unroll
            for (int p = 0; p < 4; ++p) {
                float2 f = __half22float2(base[p * PLANE + rs * HW]);
                s[p].x -= f.x; s[p].y -= f.y;
            }
        }
    }
}

// ---------------- gfC1: H-pass of (a,b) half2 ----------------
// grid (1,128,24) x 256 (4 waves); wave -> row; skewed LDS staging.
__global__ __launch_bounds__(256) void gfC1(const __half2* __restrict__ ab,
                                            __half2* __restrict__ abH)
{
    __shared__ float lds[4][2 * LROW];
    const int tid = threadIdx.x, w = tid >> 6, l = tid & 63;
    const int y  = blockIdx.y * 4 + w;
    const int bc = blockIdx.z;

    float* LA = lds[w];
    float* LB = LA + LROW;
    const __half2* src = ab + (size_t)bc * PLANE + y * HW;
    const float4 z4 = make_float4(0.f, 0.f, 0.f, 0.f);

    // stage 560 px: 140 chunks of 4 px (float4 = 4 half2)
    #pragma unroll
    for (int rnd = 0; rnd < 3; ++rnd) {
        if (rnd < 2 || l < 12) {
            int q = l + rnd * 64;
            int px = 4 * q - 16;
            bool ok = (unsigned)px < (unsigned)HW;
            float4 v = ok ? *(const float4*)(src + px) : z4;
            __half2 h0 = *(__half2*)&v.x, h1 = *(__half2*)&v.y;
            __half2 h2 = *(__half2*)&v.z, h3 = *(__half2*)&v.w;
            float2 f0 = __half22float2(h0), f1 = __half22float2(h1);
            float2 f2 = __half22float2(h2), f3 = __half22float2(h3);
            int i0 = 4 * q;
            LA[SK(i0+0)] = f0.x; LB[SK(i0+0)] = f0.y;
            LA[SK(i0+1)] = f1.x; LB[SK(i0+1)] = f1.y;
            LA[SK(i0+2)] = f2.x; LB[SK(i0+2)] = f2.y;
            LA[SK(i0+3)] = f3.x; LB[SK(i0+3)] = f3.y;
        }
    }

    const int t0 = 8 * l;
    float sa = 0.f, sb = 0.f, oa[8], ob[8];
    #pragma unroll
    for (int k = 1; k <= 31; ++k) { sa += LA[SK(t0 + k)]; sb += LB[SK(t0 + k)]; }
    oa[0] = sa; ob[0] = sb;
    #pragma unroll
    for (int j = 1; j < 8; ++j) {
        sa += LA[SK(t0 + j + 31)] - LA[SK(t0 + j)];
        sb += LB[SK(t0 + j + 31)] - LB[SK(t0 + j)];
        oa[j] = sa; ob[j] = sb;
    }
    unsigned u[8];
    #pragma unroll
    for (int j = 0; j < 8; ++j) {
        __half2 h = __floats2half2_rn(oa[j], ob[j]);
        u[j] = h2u(h);
    }
    uint4* dst = (uint4*)(abH + (size_t)bc * PLANE + y * HW + 8 * l);
    dst[0] = make_uint4(u[0], u[1], u[2], u[3]);
    dst[1] = make_uint4(u[4], u[5], u[6], u[7]);
}

// ---------------- gfC2: V-pass of (a,b) + gray + combine ----------------
// grid (2,32,24) x 256.
__global__ __launch_bounds__(256) void gfC2(const __half* __restrict__ gray,
                                            const __half2* __restrict__ abH,
                                            float* __restrict__ out)
{
    const int x  = blockIdx.x * 256 + threadIdx.x;
    const int y0 = blockIdx.y * 16;
    const int bc = blockIdx.z;
    const int b  = bc / 3;
    const __half2* src = abH + (size_t)bc * PLANE + x;
    const __half* gp = gray + (size_t)b * PLANE + x;
    float* op = out + (size_t)bc * PLANE + x;

    float sa = 0.f, sb = 0.f;
    for (int r = y0 - RAD; r < y0 + RAD; ++r) {
        if ((unsigned)r < (unsigned)HW) {
            float2 v = __half22float2(src[r * HW]);
            sa += v.x; sb += v.y;
        }
    }
    #pragma unroll
    for (int i = 0; i < 16; ++i) {
        int y = y0 + i;
        int ra = y + RAD;
        if (ra < HW) { float2 v = __half22float2(src[ra * HW]); sa += v.x; sb += v.y; }
        float g = __half2float(gp[y * HW]);
        op[y * HW] = sa * INV_K2 * g + sb * INV_K2;
        int rs = y - RAD;
        if (rs >= 0) { float2 v = __half22float2(src[rs * HW]); sa -= v.x; sb -= v.y; }
    }
}

// ===================== fallback: R3 LDS-tiled path (50.3 MB ws) ==========

#define TILE 32
#define HAL 62
#define GS 63
#define SS 33

__global__ __launch_bounds__(256) void gf_s1_fb(
    const float* __restrict__ guide, const float* __restrict__ inp,
    float2* __restrict__ ab)
{
    __shared__ float gh[HAL * GS];
    __shared__ float ph[HAL * GS];
    __shared__ float h0[HAL * SS];
    __shared__ float h1[HAL * SS];

    const int tx0 = blockIdx.x * TILE;
    const int ty0 = blockIdx.y * TILE;
    const int b   = blockIdx.z;
    const int tid = threadIdx.x;

    const float* gbase = guide + (size_t)b * 3 * PLANE;
    const float* pbase = inp   + (size_t)b * 3 * PLANE;

    int lidx[16], goff[16];
    #pragma unroll
    for (int k = 0; k < 16; ++k) {
        int i = tid + k * 256;
        int r = i / HAL, c = i - r * HAL;
        bool inh = i < HAL * HAL;
        lidx[k] = inh ? (r * GS + c) : -1;
        int y = ty0 + r - RAD, x = tx0 + c - RAD;
        bool ok = inh && ((unsigned)y < (unsigned)HW) && ((unsigned)x < (unsigned)HW);
        goff[k] = ok ? (y * HW + x) : -1;
    }
    float gr_[16], pA[16];
    #pragma unroll
    for (int k = 0; k < 16; ++k) {
        float g = 0.f, p = 0.f;
        if (goff[k] >= 0) {
            int o = goff[k];
            g = 0.299f * gbase[o] + 0.587f * gbase[PLANE + o] + 0.114f * gbase[2 * PLANE + o];
            p = pbase[o];
        }
        gr_[k] = g; pA[k] = p;
    }
    #pragma unroll
    for (int k = 0; k < 16; ++k)
        if (lidx[k] >= 0) { gh[lidx[k]] = gr_[k]; ph[lidx[k]] = pA[k]; }
    __syncthreads();

    const int hr = tid & 63, hq = tid >> 6;
    const bool hact = hr < HAL;
    const int hbase = hr * GS + hq * 8;
    const int obase = hr * SS + hq * 8;
    const int vc = tid & 31, vq = tid >> 5;
    const int vbase = (vq * 4) * SS + vc;

    if (hact) {
        float s0 = 0.f, s1 = 0.f;
        #pragma unroll
        for (int k = 0; k < 31; ++k) { float v = gh[hbase + k]; s0 += v; s1 += v * v; }
        h0[obase] = s0; h1[obase] = s1;
        #pragma unroll
        for (int j = 1; j < 8; ++j) {
            float vi = gh[hbase + j + 30], vo = gh[hbase + j - 1];
            s0 += vi - vo; s1 += vi * vi - vo * vo;
            h0[obase + j] = s0; h1[obase + j] = s1;
        }
    }
    __syncthreads();

    float meanI[4], varI[4];
    {
        float s0 = 0.f, s1 = 0.f;
        #pragma unroll
        for (int k = 0; k < 31; ++k) { s0 += h0[vbase + k * SS]; s1 += h1[vbase + k * SS]; }
        meanI[0] = s0 * INV_K2; varI[0] = s1 * INV_K2 - meanI[0] * meanI[0];
        #pragma unroll
        for (int j = 1; j < 4; ++j) {
            s0 += h0[vbase + (j + 30) * SS] - h0[vbase + (j - 1) * SS];
            s1 += h1[vbase + (j + 30) * SS] - h1[vbase + (j - 1) * SS];
            meanI[j] = s0 * INV_K2; varI[j] = s1 * INV_K2 - meanI[j] * meanI[j];
        }
    }
    float pB[16];
    #pragma unroll
    for (int k = 0; k < 16; ++k)
        pB[k] = (goff[k] >= 0) ? pbase[PLANE + goff[k]] : 0.f;

#define CH_H_FB                                                              \
    if (hact) {                                                              \
        float s0 = 0.f, s1 = 0.f;                                            \
        _Pragma("unroll")                                                    \
        for (int k = 0; k < 31; ++k) {                                       \
            float p = ph[hbase + k], g = gh[hbase + k];                      \
            s0 += p; s1 += g * p;                                            \
        }                                                                    \
        h0[obase] = s0; h1[obase] = s1;                                      \
        _Pragma("unroll")                                                    \
        for (int j = 1; j < 8; ++j) {                                        \
            float pi = ph[hbase + j + 30], po = ph[hbase + j - 1];           \
            float gi = gh[hbase + j + 30], go = gh[hbase + j - 1];           \
            s0 += pi - po; s1 += gi * pi - go * po;                          \
            h0[obase + j] = s0; h1[obase + j] = s1;                          \
        }                                                                    \
    }
#define CH_V_FB(ch)                                                          \
    {                                                                        \
        float s0 = 0.f, s1 = 0.f;                                            \
        _Pragma("unroll")                                                    \
        for (int k = 0; k < 31; ++k) { s0 += h0[vbase + k * SS]; s1 += h1[vbase + k * SS]; } \
        float2* abp = ab + (size_t)(b * 3 + (ch)) * PLANE;                   \
        _Pragma("unroll")                                                    \
        for (int j = 0; j < 4; ++j) {                                        \
            if (j) {                                                         \
                s0 += h0[vbase + (j + 30) * SS] - h0[vbase + (j - 1) * SS];  \
                s1 += h1[vbase + (j + 30) * SS] - h1[vbase + (j - 1) * SS];  \
            }                                                                \
            float mp = s0 * INV_K2, corr = s1 * INV_K2;                      \
            float cov = corr - meanI[j] * mp;                                \
            float aa  = cov / (varI[j] + 1e-6f);                             \
            float bb  = mp - aa * meanI[j];                                  \
            abp[(ty0 + vq * 4 + j) * HW + tx0 + vc] = make_float2(aa, bb);   \
        }                                                                    \
    }

    __syncthreads();
    CH_H_FB
    __syncthreads();
    CH_V_FB(0)
    #pragma unroll
    for (int k = 0; k < 16; ++k) if (lidx[k] >= 0) ph[lidx[k]] = pB[k];
    float pC[16];
    #pragma unroll
    for (int k = 0; k < 16; ++k)
        pC[k] = (goff[k] >= 0) ? pbase[2 * PLANE + goff[k]] : 0.f;
    __syncthreads();
    CH_H_FB
    __syncthreads();
    CH_V_FB(1)
    #pragma unroll
    for (int k = 0; k < 16; ++k) if (lidx[k] >= 0) ph[lidx[k]] = pC[k];
    __syncthreads();
    CH_H_FB
    __syncthreads();
    CH_V_FB(2)
#undef CH_H_FB
#undef CH_V_FB
}

__global__ __launch_bounds__(256) void gf_s2_fb(
    const float* __restrict__ guide, const float2* __restrict__ ab,
    float* __restrict__ out)
{
    __shared__ float ah[HAL * GS];
    __shared__ float bh[HAL * GS];
    __shared__ float h0[HAL * SS];
    __shared__ float h1[HAL * SS];

    const int tx0 = blockIdx.x * TILE;
    const int ty0 = blockIdx.y * TILE;
    const int bc  = blockIdx.z;
    const int b   = bc / 3;
    const int tid = threadIdx.x;

    const float2* abp = ab + (size_t)bc * PLANE;
    const float*  gb  = guide + (size_t)b * 3 * PLANE;
    const int vc = tid & 31, vq = tid >> 5;

    int lidx[16];
    float2 hv[16];
    #pragma unroll
    for (int k = 0; k < 16; ++k) {
        int i = tid + k * 256;
        int r = i / HAL, c = i - r * HAL;
        bool inh = i < HAL * HAL;
        lidx[k] = inh ? (r * GS + c) : -1;
        int y = ty0 + r - RAD, x = tx0 + c - RAD;
        bool ok = inh && ((unsigned)y < (unsigned)HW) && ((unsigned)x < (unsigned)HW);
        hv[k] = ok ? abp[y * HW + x] : make_float2(0.f, 0.f);
    }
    float gcen[4];
    #pragma unroll
    for (int j = 0; j < 4; ++j) {
        int o = (ty0 + vq * 4 + j) * HW + tx0 + vc;
        gcen[j] = 0.299f * gb[o] + 0.587f * gb[PLANE + o] + 0.114f * gb[2 * PLANE + o];
    }
    #pragma unroll
    for (int k = 0; k < 16; ++k)
        if (lidx[k] >= 0) { ah[lidx[k]] = hv[k].x; bh[lidx[k]] = hv[k].y; }
    __syncthreads();

    const int hr = tid & 63, hq = tid >> 6;
    const int hbase = hr * GS + hq * 8;
    const int obase = hr * SS + hq * 8;
    if (hr < HAL) {
        float s0 = 0.f, s1 = 0.f;
        #pragma unroll
        for (int k = 0; k < 31; ++k) { s0 += ah[hbase + k]; s1 += bh[hbase + k]; }
        h0[obase] = s0; h1[obase] = s1;
        #pragma unroll
        for (int j = 1; j < 8; ++j) {
            s0 += ah[hbase + j + 30] - ah[hbase + j - 1];
            s1 += bh[hbase + j + 30] - bh[hbase + j - 1];
            h0[obase + j] = s0; h1[obase + j] = s1;
        }
    }
    __syncthreads();
    {
        const int vbase = (vq * 4) * SS + vc;
        float s0 = 0.f, s1 = 0.f;
        #pragma unroll
        for (int k = 0; k < 31; ++k) { s0 += h0[vbase + k * SS]; s1 += h1[vbase + k * SS]; }
        float* op = out + (size_t)bc * PLANE;
        #pragma unroll
        for (int j = 0; j < 4; ++j) {
            if (j) {
                s0 += h0[vbase + (j + 30) * SS] - h0[vbase + (j - 1) * SS];
                s1 += h1[vbase + (j + 30) * SS] - h1[vbase + (j - 1) * SS];
            }
            int o = (ty0 + vq * 4 + j) * HW + tx0 + vc;
            op[o] = s0 * INV_K2 * gcen[j] + s1 * INV_K2;
        }
    }
}

// ===================== launch =====================

extern "C" void kernel_launch(void* const* d_in, const int* in_sizes, int n_in,
                              void* d_out, int out_size, void* d_ws, size_t ws_size,
                              hipStream_t stream)
{
    const float* guide = (const float*)d_in[0];
    const float* inp   = (const float*)d_in[1];
    float* out = (float*)d_out;

    const size_t H8_B   = (size_t)8 * 4 * PLANE * 4;   // 32 MiB (half2 pairs)
    const size_t GRAY_B = (size_t)8 * PLANE * 2;       //  4 MiB
    const size_t AB_B   = (size_t)24 * PLANE * 4;      // 24 MiB
    const size_t ABH_B  = (size_t)24 * PLANE * 4;      // 24 MiB

    if (ws_size >= H8_B + GRAY_B + AB_B + ABH_B) {
        __half2* H8   = (__half2*)d_ws;
        __half*  gray = (__half*)((char*)d_ws + H8_B);
        __half2* ab   = (__half2*)((char*)d_ws + H8_B + GRAY_B);
        __half2* abH  = (__half2*)((char*)d_ws + H8_B + GRAY_B + AB_B);

        gfA <<<dim3(1, 128,  8), 256, 0, stream>>>(guide, inp, H8, gray);
        gfB <<<dim3(2,  32,  8), 256, 0, stream>>>(H8, ab);
        gfC1<<<dim3(1, 128, 24), 256, 0, stream>>>(ab, abH);
        gfC2<<<dim3(2,  32, 24), 256, 0, stream>>>(gray, abH, out);
    } else {
        float2* ab_ws = (float2*)d_ws;   // 50.3 MB
        gf_s1_fb<<<dim3(HW / TILE, HW / TILE, 8),  256, 0, stream>>>(guide, inp, ab_ws);
        gf_s2_fb<<<dim3(HW / TILE, HW / TILE, 24), 256, 0, stream>>>(guide, ab_ws, out);
    }
}